// Round 10
// baseline (305.982 us; speedup 1.0000x reference)
//
#include <hip/hip_runtime.h>
#include <hip/hip_bf16.h>
#include <stdint.h>
#include <math.h>

// ---------------------------------------------------------------------------
// GATNet on MI355X.
// adj is only a mask (adj>0 <=> x_i.x_j >= 0.8*|x_i||x_j|); diagonal always
// set (cos=1). Attention = sparse bit-mask scan + online softmax.
// R1: per-row 128-bit summary bitmap.
// R2: SIM upper-triangle only; split-K out-gemm; wave-per-row attention.
// R3: f12 = x @ (W @ a) fp32; prestage fusion.
// R4: mask finalized before Wh gemm; Wh epilogue routes per-row: degree-1
//     rows get elu(v)->hout directly (att=1 exactly), others bf16(v)->Wh.
// R5: overlap-oriented dispatch graph.
// R6: SIM in int8 (mfma_i32_16x16x64_i8).
// R7: BK=64 K-loop (22 barriers vs 44) -> whh 135->122 us, MfmaUtil 34%.
// R8: merged mega dispatch -- REGRESSED (block-slot residency, not pipe
//     idleness, is the binding resource; +66MB writes). Reverted.
// R9(=this): R8 graph (best: 297us) + split-K 8 out-gemm (parts 67->33.5MB).
// whh is at the m97-family structural plateau (~87%); rest is stage2 (SIM-
// bound, transposes hidden) + harness re-poison floor.
// ---------------------------------------------------------------------------

typedef __bf16 bf16x8 __attribute__((ext_vector_type(8)));
typedef float  f32x4  __attribute__((ext_vector_type(4)));
typedef int    i32x4  __attribute__((ext_vector_type(4)));
typedef unsigned short ushort8 __attribute__((ext_vector_type(8)));

#define AS1C(p) ((const __attribute__((address_space(1))) void*)(p))
#define AS3(p)  ((__attribute__((address_space(3))) void*)(p))

#define MODE_WH  0
#define MODE_F32 2

__device__ __forceinline__ float bfbits2f(unsigned short u) {
    return __uint_as_float(((unsigned)u) << 16);
}
__device__ __forceinline__ unsigned short f2bfbits(float v) {
    __hip_bfloat16 b = __float2bfloat16(v);
    return *(unsigned short*)&b;
}

// row has mask == {row} exactly (degree-1-self)?
__device__ __forceinline__ bool row_fast(const unsigned* __restrict__ mask,
                                         const unsigned* __restrict__ summ,
                                         int row)
{
    const uint4 s = *(const uint4*)(summ + row * 4);
    unsigned sw[4] = { s.x, s.y, s.z, s.w };
    const int wi = row >> 5;
    bool fast = (sw[wi >> 5] == (1u << (wi & 31)));
    sw[wi >> 5] = 0;
    fast = fast && !(sw[0] | sw[1] | sw[2] | sw[3]);
    return fast && (mask[row * 128 + wi] == (1u << (row & 31)));
}

// C = A(M x K, lda) * B^T, B is (N x K, ldb), both bf16 row-major.
// 128x128 tile, BK=64 (two 128x32 half-tiles, no barrier between halves),
// 256 threads (4 waves, 2x2 of 64x64), 16x16x32 MFMA.
// MODE_WH: degree-1 rows get elu(v) into hout, others bf16(v) into Cv.
template<int MODE>
__device__ __forceinline__ void gemm_body(
    __hip_bfloat16* __restrict__ As, __hip_bfloat16* __restrict__ Bs,
    int bx, int by,
    const __hip_bfloat16* __restrict__ A,
    const __hip_bfloat16* __restrict__ B,
    int lda, int ldb, int K,
    void* __restrict__ Cv, int ldc, int Nreal,
    unsigned* __restrict__ mask,
    unsigned* __restrict__ summary,
    __hip_bfloat16* __restrict__ hout)
{
    const int tid  = threadIdx.x;
    const int lane = tid & 63;
    const int wave = tid >> 6;
    const int m0   = bx * 128;
    const int n0   = by * 128;

    f32x4 acc[4][4];
#pragma unroll
    for (int i = 0; i < 4; ++i)
#pragma unroll
        for (int j = 0; j < 4; ++j)
#pragma unroll
            for (int k = 0; k < 4; ++k) acc[i][j][k] = 0.f;

    const int wm = wave >> 1, wn = wave & 1;
    const int q  = lane >> 4, ln = lane & 15;

    const int kIters = K >> 6;                      // BK = 64
    for (int kt = 0; kt < kIters; ++kt) {
        __syncthreads();
#pragma unroll
        for (int p = 0; p < 4; ++p) {
            const int t    = p * 256 + tid;         // 1024 chunks of 16 B
            const int half = t >> 9;                // k 0..31 vs 32..63
            const int tl   = t & 511;
            const int row  = tl >> 2;
            const int kb   = (tl & 3) ^ ((tl >> 3) & 3);   // XOR swizzle slot
            const int kofs = kt * 64 + half * 32 + kb * 8;
            const __hip_bfloat16* ga = A + (long long)(m0 + row) * lda + kofs;
            const __hip_bfloat16* gb = B + (long long)(n0 + row) * ldb + kofs;
            __hip_bfloat16* sa = As + (p * 256 + wave * 64) * 8;
            __hip_bfloat16* sb = Bs + (p * 256 + wave * 64) * 8;
            __builtin_amdgcn_global_load_lds(AS1C(ga), AS3(sa), 16, 0, 0);
            __builtin_amdgcn_global_load_lds(AS1C(gb), AS3(sb), 16, 0, 0);
        }
        __syncthreads();

#pragma unroll
        for (int s = 0; s < 2; ++s) {               // two k-halves, no barrier
            bf16x8 afr[4], bfr[4];
#pragma unroll
            for (int rg = 0; rg < 4; ++rg) {
                const int r  = wm * 64 + rg * 16 + ln;
                const int sl = q ^ ((r >> 1) & 3);
                afr[rg] = *(const bf16x8*)(As + s * 4096 + r * 32 + sl * 8);
            }
#pragma unroll
            for (int cg = 0; cg < 4; ++cg) {
                const int r  = wn * 64 + cg * 16 + ln;
                const int sl = q ^ ((r >> 1) & 3);
                bfr[cg] = *(const bf16x8*)(Bs + s * 4096 + r * 32 + sl * 8);
            }
#pragma unroll
            for (int rg = 0; rg < 4; ++rg)
#pragma unroll
                for (int cg = 0; cg < 4; ++cg)
                    acc[rg][cg] = __builtin_amdgcn_mfma_f32_16x16x32_bf16(
                        afr[rg], bfr[cg], acc[rg][cg], 0, 0, 0);
        }
    }

    // epilogue: C/D layout col=lane&15, row=quad*4+reg (m89/m91-verified)
#pragma unroll
    for (int rg = 0; rg < 4; ++rg) {
#pragma unroll
        for (int i = 0; i < 4; ++i) {
            const int row = m0 + wm * 64 + rg * 16 + q * 4 + i;
            bool fast = false;
            if (MODE == MODE_WH) fast = row_fast(mask, summary, row);
#pragma unroll
            for (int cg = 0; cg < 4; ++cg) {
                const int col = n0 + wn * 64 + cg * 16 + ln;
                const float v = acc[rg][cg][i];
                if (MODE == MODE_WH) {
                    if (fast) {
                        const float u = v > 0.f ? v : (__expf(v) - 1.f);
                        hout[(long long)row * 8192 + col] = __float2bfloat16(u);
                    } else {
                        __hip_bfloat16* C = (__hip_bfloat16*)Cv;
                        C[(long long)row * ldc + col] = __float2bfloat16(v);
                    }
                } else {
                    if (col < Nreal) {
                        float* C = (float*)Cv;
                        C[(long long)row * ldc + col] = v;
                    }
                }
            }
        }
    }
}

// SIM in int8: dot(xq_row, xq_col)*s_r*s_c >= 0.8*n_r*n_c -> mask bits.
__device__ __forceinline__ void sim_i8_body(
    signed char* __restrict__ Aq, signed char* __restrict__ Bq,
    int bx, int by,
    const signed char* __restrict__ xq,
    const float* __restrict__ scales,
    const float* __restrict__ norms,
    unsigned* __restrict__ mask,
    unsigned* __restrict__ summary)
{
    const int tid  = threadIdx.x;
    const int lane = tid & 63;
    const int wave = tid >> 6;
    const int m0   = bx * 128;
    const int n0   = by * 128;

    i32x4 acc[4][4];
#pragma unroll
    for (int i = 0; i < 4; ++i)
#pragma unroll
        for (int j = 0; j < 4; ++j)
#pragma unroll
            for (int k = 0; k < 4; ++k) acc[i][j][k] = 0;

    const int wm = wave >> 1, wn = wave & 1;
    const int q  = lane >> 4, ln = lane & 15;

    for (int kt = 0; kt < 22; ++kt) {              // 1408 / 64
        __syncthreads();
#pragma unroll
        for (int p = 0; p < 2; ++p) {
            const int t   = p * 256 + tid;
            const int row = t >> 2;
            const int kb  = (t & 3) ^ ((t >> 3) & 3);
            const signed char* ga = xq + (long long)(m0 + row) * 1408 + kt * 64 + kb * 16;
            const signed char* gb = xq + (long long)(n0 + row) * 1408 + kt * 64 + kb * 16;
            signed char* sa = Aq + (p * 256 + wave * 64) * 16;
            signed char* sb = Bq + (p * 256 + wave * 64) * 16;
            __builtin_amdgcn_global_load_lds(AS1C(ga), AS3(sa), 16, 0, 0);
            __builtin_amdgcn_global_load_lds(AS1C(gb), AS3(sb), 16, 0, 0);
        }
        __syncthreads();

        i32x4 afr[4], bfr[4];
#pragma unroll
        for (int rg = 0; rg < 4; ++rg) {
            const int r = wm * 64 + rg * 16 + ln;
            const int s = q ^ ((r >> 1) & 3);
            afr[rg] = *(const i32x4*)(Aq + r * 64 + s * 16);
        }
#pragma unroll
        for (int cg = 0; cg < 4; ++cg) {
            const int r = wn * 64 + cg * 16 + ln;
            const int s = q ^ ((r >> 1) & 3);
            bfr[cg] = *(const i32x4*)(Bq + r * 64 + s * 16);
        }
#pragma unroll
        for (int rg = 0; rg < 4; ++rg)
#pragma unroll
            for (int cg = 0; cg < 4; ++cg)
                acc[rg][cg] = __builtin_amdgcn_mfma_i32_16x16x64_i8(
                    afr[rg], bfr[cg], acc[rg][cg], 0, 0, 0);
    }

#pragma unroll
    for (int rg = 0; rg < 4; ++rg) {
#pragma unroll
        for (int i = 0; i < 4; ++i) {
            const int row = m0 + wm * 64 + rg * 16 + q * 4 + i;
            const float sr = scales[row], nr = norms[row];
#pragma unroll
            for (int cg = 0; cg < 4; ++cg) {
                const int col = n0 + wn * 64 + cg * 16 + ln;
                const float v = (float)acc[rg][cg][i] * (sr * scales[col]);
                if (v >= 0.8f * nr * norms[col]) {
                    atomicOr(&mask[row * 128 + (col >> 5)], 1u << (col & 31));
                    atomicOr(&summary[row * 4 + (col >> 10)], 1u << ((col >> 5) & 31));
                    atomicOr(&mask[col * 128 + (row >> 5)], 1u << (row & 31));
                    atomicOr(&summary[col * 4 + (row >> 10)], 1u << ((row >> 5) & 31));
                }
            }
        }
    }
}

// ---------------------------------------------------------------------------
// stage1: [0,4096)   convert x row -> x_bf + xq(int8) + norm + scale + clear
//         [4096,5120) transpose W_out (f32 (8192,64) -> bf16 (128,8192))
//         [5120,7936) wa[h][s][c] = sum_j W_att[h][c][j]*a_att[h][s*1024+j]
// ---------------------------------------------------------------------------
__global__ __launch_bounds__(256)
void stage1(const float* __restrict__ x,
            const float* __restrict__ W_att,
            const float* __restrict__ W_out,
            const float* __restrict__ a_att,
            __hip_bfloat16* __restrict__ x_bf,
            signed char* __restrict__ xq,
            float* __restrict__ norms,
            float* __restrict__ scales,
            __hip_bfloat16* __restrict__ WoutT,
            float* __restrict__ wa,
            unsigned* __restrict__ mask,
            unsigned* __restrict__ summ)
{
    __shared__ float ts[32][33];
    __shared__ float red[4], redm[4], sh_s;
    const int id  = blockIdx.x;
    const int tid = threadIdx.x;

    if (id < 4096) {
        const int i = id;
        if (tid < 128) mask[i * 128 + tid] = 0;
        else if (tid < 132) summ[i * 4 + (tid - 128)] = 0;
        float ss = 0.f, am = 0.f;
        float vv[6];
#pragma unroll
        for (int k = 0; k < 6; ++k) {
            const int c = tid + k * 256;
            float v = (c < 1386) ? x[(long long)i * 1386 + c] : 0.f;
            vv[k] = v;
            if (c < 1408) x_bf[(long long)i * 1408 + c] = __float2bfloat16(v);
            ss += v * v;
            am = fmaxf(am, fabsf(v));
        }
        for (int off = 32; off; off >>= 1) {
            ss += __shfl_down(ss, off);
            am = fmaxf(am, __shfl_down(am, off));
        }
        if ((tid & 63) == 0) { red[tid >> 6] = ss; redm[tid >> 6] = am; }
        __syncthreads();
        if (tid == 0) {
            norms[i] = fmaxf(sqrtf(red[0] + red[1] + red[2] + red[3]), 1e-12f);
            const float amax = fmaxf(fmaxf(redm[0], redm[1]), fmaxf(redm[2], redm[3]));
            const float s = fmaxf(amax, 1e-30f) / 127.f;
            scales[i] = s;
            sh_s = s;
        }
        __syncthreads();
        const float inv_s = 1.f / sh_s;
#pragma unroll
        for (int k = 0; k < 6; ++k) {
            const int c = tid + k * 256;
            if (c < 1408) {
                float qv = fminf(fmaxf(rintf(vv[k] * inv_s), -127.f), 127.f);
                xq[(long long)i * 1408 + c] = (signed char)(int)qv;
            }
        }
        return;
    }
    if (id < 5120) {
        // W_out transpose: 8192x64 f32 -> 128x8192 bf16 (zero-pad cols)
        const int r  = id - 4096;                 // 256 x 4
        const int k0 = (r & 255) * 32, n0 = (r >> 8) * 32;
        const int tx = tid & 31, ty = tid >> 5;
#pragma unroll
        for (int i = 0; i < 4; ++i) {
            const int k = k0 + ty + i * 8;
            const int n = n0 + tx;
            ts[ty + i * 8][tx] = (n < 64) ? W_out[(long long)k * 64 + n] : 0.f;
        }
        __syncthreads();
#pragma unroll
        for (int i = 0; i < 4; ++i) {
            const int n  = n0 + ty + i * 8;
            const int kk = k0 + tx;
            WoutT[(long long)n * 8192 + kk] = __float2bfloat16(ts[tx][ty + i * 8]);
        }
        return;
    }
    // ---- wa: wave per (h, c) ----
    {
        const int b = id - 5120;                     // 8 heads x 352
        const int h = b / 352, r = b % 352;
        const int wave = tid >> 6, lane = tid & 63;
        const int c = r * 4 + wave;                  // 0..1407
        float s1 = 0.f, s2 = 0.f;
        if (c < 1386) {
            const float* wr = W_att + ((long long)h * 1386 + c) * 1024;
            const float* a1 = a_att + (long long)h * 2048;
            const float* a2 = a1 + 1024;
#pragma unroll
            for (int t = 0; t < 16; ++t) {
                const int j = lane + t * 64;
                const float w = wr[j];
                s1 += w * a1[j];
                s2 += w * a2[j];
            }
        }
        for (int off = 32; off; off >>= 1) { s1 += __shfl_down(s1, off); s2 += __shfl_down(s2, off); }
        if (lane == 0 && c < 1386) {
            wa[(h * 2 + 0) * 1408 + c] = s1;
            wa[(h * 2 + 1) * 1408 + c] = s2;
        }
    }
}

// ---------------------------------------------------------------------------
// stage2: [0,528) SIM-i8 upper-triangle GEMM
//         [528,11792) transpose W_att (f32 (8,1386,1024) -> bf16 (8,1024,1408))
//         [11792,12816) f12 = x @ wa (wave per row, fp32)
// Memory-bound transpose + f12x overlap the compute-bound SIM.
// ---------------------------------------------------------------------------
__global__ __launch_bounds__(256, 2)
void stage2(const signed char* __restrict__ xq,
            const float* __restrict__ scales,
            const float* __restrict__ norms,
            unsigned* __restrict__ mask,
            unsigned* __restrict__ summ,
            const float* __restrict__ W_att,
            __hip_bfloat16* __restrict__ Wt_bf,
            const float* __restrict__ x,
            const float* __restrict__ wa,
            float2* __restrict__ f12)
{
    __shared__ __align__(16) __hip_bfloat16 As[128 * 32];
    __shared__ __align__(16) __hip_bfloat16 Bs[128 * 32];
    const int id = blockIdx.x;

    if (id < 528) {
        int t = (int)((sqrtf(8.f * id + 1.f) - 1.f) * 0.5f);
        while (t * (t + 1) / 2 > id) --t;
        while ((t + 1) * (t + 2) / 2 <= id) ++t;
        const int by = t, bx = id - t * (t + 1) / 2;   // bx <= by
        sim_i8_body((signed char*)As, (signed char*)Bs, bx, by,
                    xq, scales, norms, mask, summ);
        return;
    }
    if (id < 11792) {
        // W_att transpose, LDS overlaid on As
        float (*ts)[33] = (float(*)[33])As;
        const int tid = threadIdx.x;
        const int b = id - 528;                  // 8 heads x 44 x 32
        const int h = b / 1408, r = b % 1408;
        const int kx = r % 44, ny = r / 44;
        const float* s = W_att + (long long)h * 1386 * 1024;
        __hip_bfloat16* d = Wt_bf + (long long)h * 1024 * 1408;
        const int k0 = kx * 32, n0 = ny * 32;
        const int tx = tid & 31, ty = tid >> 5;
#pragma unroll
        for (int i = 0; i < 4; ++i) {
            const int k = k0 + ty + i * 8;
            const int n = n0 + tx;
            ts[ty + i * 8][tx] = (k < 1386) ? s[(long long)k * 1024 + n] : 0.f;
        }
        __syncthreads();
#pragma unroll
        for (int i = 0; i < 4; ++i) {
            const int n  = n0 + ty + i * 8;
            const int kk = k0 + tx;
            if (kk < 1408)
                d[(long long)n * 1408 + kk] = __float2bfloat16(ts[tx][ty + i * 8]);
        }
        return;
    }
    // ---- f12x: wave per row ----
    {
        const int b    = id - 11792;
        const int wave = threadIdx.x >> 6, lane = threadIdx.x & 63;
        const int i    = b * 4 + wave;
        float s[16];
#pragma unroll
        for (int j = 0; j < 16; ++j) s[j] = 0.f;
        const float* xr = x + (long long)i * 1386;
        for (int c = lane; c < 1386; c += 64) {
            const float v = xr[c];
#pragma unroll
            for (int j = 0; j < 16; ++j) s[j] += v * wa[j * 1408 + c];
        }
#pragma unroll
        for (int j = 0; j < 16; ++j)
            for (int off = 32; off; off >>= 1) s[j] += __shfl_down(s[j], off);
        if (lane == 0) {
#pragma unroll
            for (int h = 0; h < 8; ++h)
                f12[(long long)h * 4096 + i] = make_float2(s[h * 2], s[h * 2 + 1]);
        }
    }
}

// Wh GEMM for all 8 heads; epilogue routes per-row (hout direct vs Wh)
__global__ __launch_bounds__(256, 2)
void whh(const __hip_bfloat16* __restrict__ x_bf,
         const __hip_bfloat16* __restrict__ Wt_bf,
         __hip_bfloat16* __restrict__ Wh,
         __hip_bfloat16* __restrict__ hout,
         unsigned* __restrict__ mask,
         unsigned* __restrict__ summ)
{
    __shared__ __align__(16) __hip_bfloat16 As[128 * 64];
    __shared__ __align__(16) __hip_bfloat16 Bs[128 * 64];
    const int id = blockIdx.x;
    const int z  = id >> 8;            // head
    const int r  = id & 255;
    const int bx = r & 31, by = r >> 5;
    gemm_body<MODE_WH>(As, Bs, bx, by,
                       x_bf, Wt_bf + (long long)z * 1024 * 1408,
                       1408, 1408, 1408,
                       Wh + (long long)z * 4096 * 1024, 1024, 1024,
                       mask, summ, hout + (long long)z * 1024);
}

// out partial GEMM: split-K (8 chunks of 1024, BK=64 -> 16 iters)
__global__ __launch_bounds__(256, 2)
void out_gemm(const __hip_bfloat16* __restrict__ hout,
              const __hip_bfloat16* __restrict__ WoutT,
              float* __restrict__ parts)
{
    __shared__ __align__(16) __hip_bfloat16 As[128 * 64];
    __shared__ __align__(16) __hip_bfloat16 Bs[128 * 64];
    const int z = blockIdx.z;
    gemm_body<MODE_F32>(As, Bs, blockIdx.x, 0,
                        hout + z * 1024, WoutT + z * 1024, 8192, 8192, 1024,
                        parts + (long long)z * 4096 * 64, 64, 64,
                        nullptr, nullptr, nullptr);
}

// fallback attention for non-degree-1 rows (early-exit otherwise); wave/(row,head)
__global__ __launch_bounds__(256)
void attn_fix(const __hip_bfloat16* __restrict__ Wh,
              const float2* __restrict__ f12,
              const unsigned* __restrict__ mask,
              const unsigned* __restrict__ summary,
              __hip_bfloat16* __restrict__ hout)
{
    const int wv   = threadIdx.x >> 6;
    const int lane = threadIdx.x & 63;
    const int i    = blockIdx.x * 4 + wv;
    const int h    = blockIdx.y;
    if (row_fast(mask, summary, i)) return;   // whh already wrote hout row

    const float2* f = f12 + (long long)h * 4096;
    const float f1 = f[i].x;
    const unsigned* mrow = mask + (long long)i * 128;
    const __hip_bfloat16* WhH = Wh + (long long)h * 4096 * 1024;
    const uint4 sm = *(const uint4*)(summary + (long long)i * 4);
    unsigned sw[4] = { sm.x, sm.y, sm.z, sm.w };
    const int cbase = lane * 16;

    float m = -INFINITY, l = 0.f;
    float acc[16];
#pragma unroll
    for (int k = 0; k < 16; ++k) acc[k] = 0.f;

#pragma unroll
    for (int s = 0; s < 4; ++s) {
        unsigned sb = sw[s];
        while (sb) {
            const int w = s * 32 + __builtin_ctz(sb);
            sb &= sb - 1;
            unsigned bits = mrow[w];
            while (bits) {
                const int j = w * 32 + __builtin_ctz(bits);
                bits &= bits - 1;
                float e = f1 + f[j].y;
                e = e > 0.f ? e : 0.2f * e;           // leaky_relu 0.2
                float wgt;
                if (e > m) {
                    const float sc = __expf(m - e);   // 0 on first iter
                    l *= sc;
#pragma unroll
                    for (int k = 0; k < 16; ++k) acc[k] *= sc;
                    m = e; wgt = 1.f;
                } else {
                    wgt = __expf(e - m);
                }
                l += wgt;
                const ushort8* p = (const ushort8*)(WhH + (long long)j * 1024 + cbase);
                const ushort8 w0 = p[0], w1 = p[1];
#pragma unroll
                for (int k = 0; k < 8; ++k) acc[k]     += wgt * bfbits2f(w0[k]);
#pragma unroll
                for (int k = 0; k < 8; ++k) acc[k + 8] += wgt * bfbits2f(w1[k]);
            }
        }
    }
    const float inv = 1.f / l;
    ushort8 o0, o1;
#pragma unroll
    for (int k = 0; k < 8; ++k) {
        float v = acc[k] * inv;     v = v > 0.f ? v : (__expf(v) - 1.f); o0[k] = f2bfbits(v);
        float u = acc[k + 8] * inv; u = u > 0.f ? u : (__expf(u) - 1.f); o1[k] = f2bfbits(u);
    }
    ushort8* op = (ushort8*)(hout + (long long)i * 8192 + (long long)h * 1024 + cbase);
    op[0] = o0; op[1] = o1;
}

// reduce 8 split-K parts -> Cout; f1o/f2o; fast rows: out = tanh(Cout) inline.
__global__ __launch_bounds__(256)
void out_finish(const float* __restrict__ parts,
                const float* __restrict__ a_out,
                float* __restrict__ Cout,
                float* __restrict__ f1o,
                float* __restrict__ f2o,
                const unsigned* __restrict__ mask,
                const unsigned* __restrict__ summ,
                float* __restrict__ out)
{
    const int wv = threadIdx.x >> 6;
    const int c  = threadIdx.x & 63;
    const int i  = blockIdx.x * 4 + wv;
    float v = 0.f;
#pragma unroll
    for (int z = 0; z < 8; ++z) v += parts[(long long)z * 4096 * 64 + (long long)i * 64 + c];
    Cout[(long long)i * 64 + c] = v;
    float s1 = v * a_out[c];
    float s2 = v * a_out[64 + c];
    for (int off = 32; off; off >>= 1) { s1 += __shfl_down(s1, off); s2 += __shfl_down(s2, off); }
    if (c == 0) { f1o[i] = s1; f2o[i] = s2; }
    if (row_fast(mask, summ, i))
        out[(long long)i * 64 + c] = tanhf(v);   // att = 1 exactly
}

// exceptional-row second layer attention + tanh (early-exit otherwise); wave/row
__global__ __launch_bounds__(256)
void attn_out_fix(const float* __restrict__ Cout,
                  const float* __restrict__ f1o,
                  const float* __restrict__ f2o,
                  const unsigned* __restrict__ mask,
                  const unsigned* __restrict__ summary,
                  float* __restrict__ out)
{
    const int wv = threadIdx.x >> 6;
    const int c  = threadIdx.x & 63;
    const int i  = blockIdx.x * 4 + wv;
    if (row_fast(mask, summary, i)) return;   // out_finish already wrote it
    const float f1 = f1o[i];
    const unsigned* mrow = mask + (long long)i * 128;
    const uint4 sm = *(const uint4*)(summary + (long long)i * 4);
    unsigned sw[4] = { sm.x, sm.y, sm.z, sm.w };
    float m = -INFINITY, l = 0.f, acc = 0.f;
#pragma unroll
    for (int s = 0; s < 4; ++s) {
        unsigned sb = sw[s];
        while (sb) {
            const int w = s * 32 + __builtin_ctz(sb);
            sb &= sb - 1;
            unsigned bits = mrow[w];
            while (bits) {
                const int j = w * 32 + __builtin_ctz(bits);
                bits &= bits - 1;
                float e = f1 + f2o[j];
                e = e > 0.f ? e : 0.2f * e;
                float wgt;
                if (e > m) { const float sc = __expf(m - e); l *= sc; acc *= sc; m = e; wgt = 1.f; }
                else       { wgt = __expf(e - m); }
                l += wgt;
                acc += wgt * Cout[(long long)j * 64 + c];
            }
        }
    }
    out[(long long)i * 64 + c] = tanhf(acc / l);
}

extern "C" void kernel_launch(void* const* d_in, const int* in_sizes, int n_in,
                              void* d_out, int out_size, void* d_ws, size_t ws_size,
                              hipStream_t stream)
{
    (void)in_sizes; (void)n_in; (void)out_size;
    const float* x     = (const float*)d_in[0];
    const float* W_att = (const float*)d_in[1];
    const float* a_att = (const float*)d_in[2];
    const float* W_out = (const float*)d_in[3];
    const float* a_out = (const float*)d_in[4];
    float* out = (float*)d_out;

    char* ws = (char*)d_ws;
    size_t off = 0;
    auto alloc = [&](size_t bytes) -> void* {
        void* p = ws + off;
        off += (bytes + 255) & ~(size_t)255;
        return p;
    };

    __hip_bfloat16* x_bf  = (__hip_bfloat16*)alloc(4096LL * 1408 * 2);
    signed char*    xq    = (signed char*)alloc(4096LL * 1408);
    __hip_bfloat16* Wt_bf = (__hip_bfloat16*)alloc(8LL * 1024 * 1408 * 2);
    __hip_bfloat16* WoutT = (__hip_bfloat16*)alloc(128LL * 8192 * 2);
    float*          norms = (float*)alloc(4096 * 4);
    float*          scales= (float*)alloc(4096 * 4);
    unsigned*       mask  = (unsigned*)alloc(4096LL * 128 * 4);
    unsigned*       summ  = (unsigned*)alloc(4096LL * 4 * 4);
    float*          wa    = (float*)alloc(16LL * 1408 * 4);
    float2*         f12   = (float2*)alloc(8LL * 4096 * 8);
    float*          parts = (float*)alloc(8LL * 4096 * 64 * 4);
    float*          Cout  = (float*)alloc(4096LL * 64 * 4);
    float*          f1o   = (float*)alloc(4096 * 4);
    float*          f2o   = (float*)alloc(4096 * 4);
    __hip_bfloat16* Wh    = (__hip_bfloat16*)alloc(8LL * 4096 * 1024 * 2);
    __hip_bfloat16* hout  = (__hip_bfloat16*)alloc(8LL * 4096 * 1024 * 2);
    if (off > ws_size) return;   // ws too small (~185 MB needed)

    // stage1 clears mask/summ (per-row) -- no memset dispatch needed
    stage1<<<7936, 256, 0, stream>>>(x, W_att, W_out, a_att,
                                     x_bf, xq, norms, scales, WoutT, wa,
                                     mask, summ);

    // SIM-i8 (compute) || W_att transpose (memory) || f12x; mask final after
    stage2<<<12816, 256, 0, stream>>>(xq, scales, norms, mask, summ,
                                      W_att, Wt_bf, x, wa, f12);

    whh<<<2048, 256, 0, stream>>>(x_bf, Wt_bf, Wh, hout, mask, summ);

    attn_fix<<<dim3(1024, 8), 256, 0, stream>>>(Wh, f12, mask, summ, hout);

    out_gemm<<<dim3(32, 1, 8), 256, 0, stream>>>(hout, WoutT, parts);

    out_finish<<<1024, 256, 0, stream>>>(parts, a_out, Cout, f1o, f2o,
                                         mask, summ, out);
    attn_out_fix<<<1024, 256, 0, stream>>>(Cout, f1o, f2o, mask, summ, out);
}

// Round 11
// 295.402 us; speedup vs baseline: 1.0358x; 1.0358x over previous
//
#include <hip/hip_runtime.h>
#include <hip/hip_bf16.h>
#include <stdint.h>
#include <math.h>

// ---------------------------------------------------------------------------
// GATNet on MI355X.
// adj is only a mask (adj>0 <=> x_i.x_j >= 0.8*|x_i||x_j|); diagonal always
// set (cos=1). Attention = sparse bit-mask scan + online softmax.
// R1: per-row 128-bit summary bitmap.
// R2: SIM upper-triangle only; split-K out-gemm; wave-per-row attention.
// R3: f12 = x @ (W @ a) fp32; prestage fusion.
// R4: mask finalized before Wh gemm; Wh epilogue routes per-row: degree-1
//     rows get elu(v)->hout directly (att=1 exactly), others bf16(v)->Wh.
// R5: overlap-oriented dispatch graph.
// R6: SIM in int8 (mfma_i32_16x16x64_i8).
// R7: BK=64 K-loop (22 barriers vs 44) -> whh 135->122 us, MfmaUtil 34%.
// R8: merged mega dispatch REGRESSED (block-slot residency binds, not pipes).
// R9: split-K 8 out-gemm REGRESSED (256 blocks = 1/CU, exposed barrier
//     drains outweigh halved parts traffic).
// R10(=this): exact best-measured config (297 us): R8 graph + split-K 16
//     out-gemm (512 blocks = 2/CU, 8 iters). whh at ~87% of the m97-family
//     source-level plateau; rest = SIM-bound stage2 + harness floor.
// ---------------------------------------------------------------------------

typedef __bf16 bf16x8 __attribute__((ext_vector_type(8)));
typedef float  f32x4  __attribute__((ext_vector_type(4)));
typedef int    i32x4  __attribute__((ext_vector_type(4)));
typedef unsigned short ushort8 __attribute__((ext_vector_type(8)));

#define AS1C(p) ((const __attribute__((address_space(1))) void*)(p))
#define AS3(p)  ((__attribute__((address_space(3))) void*)(p))

#define MODE_WH  0
#define MODE_F32 2

__device__ __forceinline__ float bfbits2f(unsigned short u) {
    return __uint_as_float(((unsigned)u) << 16);
}
__device__ __forceinline__ unsigned short f2bfbits(float v) {
    __hip_bfloat16 b = __float2bfloat16(v);
    return *(unsigned short*)&b;
}

// row has mask == {row} exactly (degree-1-self)?
__device__ __forceinline__ bool row_fast(const unsigned* __restrict__ mask,
                                         const unsigned* __restrict__ summ,
                                         int row)
{
    const uint4 s = *(const uint4*)(summ + row * 4);
    unsigned sw[4] = { s.x, s.y, s.z, s.w };
    const int wi = row >> 5;
    bool fast = (sw[wi >> 5] == (1u << (wi & 31)));
    sw[wi >> 5] = 0;
    fast = fast && !(sw[0] | sw[1] | sw[2] | sw[3]);
    return fast && (mask[row * 128 + wi] == (1u << (row & 31)));
}

// C = A(M x K, lda) * B^T, B is (N x K, ldb), both bf16 row-major.
// 128x128 tile, BK=64 (two 128x32 half-tiles, no barrier between halves),
// 256 threads (4 waves, 2x2 of 64x64), 16x16x32 MFMA.
// MODE_WH: degree-1 rows get elu(v) into hout, others bf16(v) into Cv.
template<int MODE>
__device__ __forceinline__ void gemm_body(
    __hip_bfloat16* __restrict__ As, __hip_bfloat16* __restrict__ Bs,
    int bx, int by,
    const __hip_bfloat16* __restrict__ A,
    const __hip_bfloat16* __restrict__ B,
    int lda, int ldb, int K,
    void* __restrict__ Cv, int ldc, int Nreal,
    unsigned* __restrict__ mask,
    unsigned* __restrict__ summary,
    __hip_bfloat16* __restrict__ hout)
{
    const int tid  = threadIdx.x;
    const int lane = tid & 63;
    const int wave = tid >> 6;
    const int m0   = bx * 128;
    const int n0   = by * 128;

    f32x4 acc[4][4];
#pragma unroll
    for (int i = 0; i < 4; ++i)
#pragma unroll
        for (int j = 0; j < 4; ++j)
#pragma unroll
            for (int k = 0; k < 4; ++k) acc[i][j][k] = 0.f;

    const int wm = wave >> 1, wn = wave & 1;
    const int q  = lane >> 4, ln = lane & 15;

    const int kIters = K >> 6;                      // BK = 64
    for (int kt = 0; kt < kIters; ++kt) {
        __syncthreads();
#pragma unroll
        for (int p = 0; p < 4; ++p) {
            const int t    = p * 256 + tid;         // 1024 chunks of 16 B
            const int half = t >> 9;                // k 0..31 vs 32..63
            const int tl   = t & 511;
            const int row  = tl >> 2;
            const int kb   = (tl & 3) ^ ((tl >> 3) & 3);   // XOR swizzle slot
            const int kofs = kt * 64 + half * 32 + kb * 8;
            const __hip_bfloat16* ga = A + (long long)(m0 + row) * lda + kofs;
            const __hip_bfloat16* gb = B + (long long)(n0 + row) * ldb + kofs;
            __hip_bfloat16* sa = As + (p * 256 + wave * 64) * 8;
            __hip_bfloat16* sb = Bs + (p * 256 + wave * 64) * 8;
            __builtin_amdgcn_global_load_lds(AS1C(ga), AS3(sa), 16, 0, 0);
            __builtin_amdgcn_global_load_lds(AS1C(gb), AS3(sb), 16, 0, 0);
        }
        __syncthreads();

#pragma unroll
        for (int s = 0; s < 2; ++s) {               // two k-halves, no barrier
            bf16x8 afr[4], bfr[4];
#pragma unroll
            for (int rg = 0; rg < 4; ++rg) {
                const int r  = wm * 64 + rg * 16 + ln;
                const int sl = q ^ ((r >> 1) & 3);
                afr[rg] = *(const bf16x8*)(As + s * 4096 + r * 32 + sl * 8);
            }
#pragma unroll
            for (int cg = 0; cg < 4; ++cg) {
                const int r  = wn * 64 + cg * 16 + ln;
                const int sl = q ^ ((r >> 1) & 3);
                bfr[cg] = *(const bf16x8*)(Bs + s * 4096 + r * 32 + sl * 8);
            }
#pragma unroll
            for (int rg = 0; rg < 4; ++rg)
#pragma unroll
                for (int cg = 0; cg < 4; ++cg)
                    acc[rg][cg] = __builtin_amdgcn_mfma_f32_16x16x32_bf16(
                        afr[rg], bfr[cg], acc[rg][cg], 0, 0, 0);
        }
    }

    // epilogue: C/D layout col=lane&15, row=quad*4+reg (m89/m91-verified)
#pragma unroll
    for (int rg = 0; rg < 4; ++rg) {
#pragma unroll
        for (int i = 0; i < 4; ++i) {
            const int row = m0 + wm * 64 + rg * 16 + q * 4 + i;
            bool fast = false;
            if (MODE == MODE_WH) fast = row_fast(mask, summary, row);
#pragma unroll
            for (int cg = 0; cg < 4; ++cg) {
                const int col = n0 + wn * 64 + cg * 16 + ln;
                const float v = acc[rg][cg][i];
                if (MODE == MODE_WH) {
                    if (fast) {
                        const float u = v > 0.f ? v : (__expf(v) - 1.f);
                        hout[(long long)row * 8192 + col] = __float2bfloat16(u);
                    } else {
                        __hip_bfloat16* C = (__hip_bfloat16*)Cv;
                        C[(long long)row * ldc + col] = __float2bfloat16(v);
                    }
                } else {
                    if (col < Nreal) {
                        float* C = (float*)Cv;
                        C[(long long)row * ldc + col] = v;
                    }
                }
            }
        }
    }
}

// SIM in int8: dot(xq_row, xq_col)*s_r*s_c >= 0.8*n_r*n_c -> mask bits.
__device__ __forceinline__ void sim_i8_body(
    signed char* __restrict__ Aq, signed char* __restrict__ Bq,
    int bx, int by,
    const signed char* __restrict__ xq,
    const float* __restrict__ scales,
    const float* __restrict__ norms,
    unsigned* __restrict__ mask,
    unsigned* __restrict__ summary)
{
    const int tid  = threadIdx.x;
    const int lane = tid & 63;
    const int wave = tid >> 6;
    const int m0   = bx * 128;
    const int n0   = by * 128;

    i32x4 acc[4][4];
#pragma unroll
    for (int i = 0; i < 4; ++i)
#pragma unroll
        for (int j = 0; j < 4; ++j)
#pragma unroll
            for (int k = 0; k < 4; ++k) acc[i][j][k] = 0;

    const int wm = wave >> 1, wn = wave & 1;
    const int q  = lane >> 4, ln = lane & 15;

    for (int kt = 0; kt < 22; ++kt) {              // 1408 / 64
        __syncthreads();
#pragma unroll
        for (int p = 0; p < 2; ++p) {
            const int t   = p * 256 + tid;
            const int row = t >> 2;
            const int kb  = (t & 3) ^ ((t >> 3) & 3);
            const signed char* ga = xq + (long long)(m0 + row) * 1408 + kt * 64 + kb * 16;
            const signed char* gb = xq + (long long)(n0 + row) * 1408 + kt * 64 + kb * 16;
            signed char* sa = Aq + (p * 256 + wave * 64) * 16;
            signed char* sb = Bq + (p * 256 + wave * 64) * 16;
            __builtin_amdgcn_global_load_lds(AS1C(ga), AS3(sa), 16, 0, 0);
            __builtin_amdgcn_global_load_lds(AS1C(gb), AS3(sb), 16, 0, 0);
        }
        __syncthreads();

        i32x4 afr[4], bfr[4];
#pragma unroll
        for (int rg = 0; rg < 4; ++rg) {
            const int r = wm * 64 + rg * 16 + ln;
            const int s = q ^ ((r >> 1) & 3);
            afr[rg] = *(const i32x4*)(Aq + r * 64 + s * 16);
        }
#pragma unroll
        for (int cg = 0; cg < 4; ++cg) {
            const int r = wn * 64 + cg * 16 + ln;
            const int s = q ^ ((r >> 1) & 3);
            bfr[cg] = *(const i32x4*)(Bq + r * 64 + s * 16);
        }
#pragma unroll
        for (int rg = 0; rg < 4; ++rg)
#pragma unroll
            for (int cg = 0; cg < 4; ++cg)
                acc[rg][cg] = __builtin_amdgcn_mfma_i32_16x16x64_i8(
                    afr[rg], bfr[cg], acc[rg][cg], 0, 0, 0);
    }

#pragma unroll
    for (int rg = 0; rg < 4; ++rg) {
#pragma unroll
        for (int i = 0; i < 4; ++i) {
            const int row = m0 + wm * 64 + rg * 16 + q * 4 + i;
            const float sr = scales[row], nr = norms[row];
#pragma unroll
            for (int cg = 0; cg < 4; ++cg) {
                const int col = n0 + wn * 64 + cg * 16 + ln;
                const float v = (float)acc[rg][cg][i] * (sr * scales[col]);
                if (v >= 0.8f * nr * norms[col]) {
                    atomicOr(&mask[row * 128 + (col >> 5)], 1u << (col & 31));
                    atomicOr(&summary[row * 4 + (col >> 10)], 1u << ((col >> 5) & 31));
                    atomicOr(&mask[col * 128 + (row >> 5)], 1u << (row & 31));
                    atomicOr(&summary[col * 4 + (row >> 10)], 1u << ((row >> 5) & 31));
                }
            }
        }
    }
}

// ---------------------------------------------------------------------------
// stage1: [0,4096)   convert x row -> x_bf + xq(int8) + norm + scale + clear
//         [4096,5120) transpose W_out (f32 (8192,64) -> bf16 (128,8192))
//         [5120,7936) wa[h][s][c] = sum_j W_att[h][c][j]*a_att[h][s*1024+j]
// ---------------------------------------------------------------------------
__global__ __launch_bounds__(256)
void stage1(const float* __restrict__ x,
            const float* __restrict__ W_att,
            const float* __restrict__ W_out,
            const float* __restrict__ a_att,
            __hip_bfloat16* __restrict__ x_bf,
            signed char* __restrict__ xq,
            float* __restrict__ norms,
            float* __restrict__ scales,
            __hip_bfloat16* __restrict__ WoutT,
            float* __restrict__ wa,
            unsigned* __restrict__ mask,
            unsigned* __restrict__ summ)
{
    __shared__ float ts[32][33];
    __shared__ float red[4], redm[4], sh_s;
    const int id  = blockIdx.x;
    const int tid = threadIdx.x;

    if (id < 4096) {
        const int i = id;
        if (tid < 128) mask[i * 128 + tid] = 0;
        else if (tid < 132) summ[i * 4 + (tid - 128)] = 0;
        float ss = 0.f, am = 0.f;
        float vv[6];
#pragma unroll
        for (int k = 0; k < 6; ++k) {
            const int c = tid + k * 256;
            float v = (c < 1386) ? x[(long long)i * 1386 + c] : 0.f;
            vv[k] = v;
            if (c < 1408) x_bf[(long long)i * 1408 + c] = __float2bfloat16(v);
            ss += v * v;
            am = fmaxf(am, fabsf(v));
        }
        for (int off = 32; off; off >>= 1) {
            ss += __shfl_down(ss, off);
            am = fmaxf(am, __shfl_down(am, off));
        }
        if ((tid & 63) == 0) { red[tid >> 6] = ss; redm[tid >> 6] = am; }
        __syncthreads();
        if (tid == 0) {
            norms[i] = fmaxf(sqrtf(red[0] + red[1] + red[2] + red[3]), 1e-12f);
            const float amax = fmaxf(fmaxf(redm[0], redm[1]), fmaxf(redm[2], redm[3]));
            const float s = fmaxf(amax, 1e-30f) / 127.f;
            scales[i] = s;
            sh_s = s;
        }
        __syncthreads();
        const float inv_s = 1.f / sh_s;
#pragma unroll
        for (int k = 0; k < 6; ++k) {
            const int c = tid + k * 256;
            if (c < 1408) {
                float qv = fminf(fmaxf(rintf(vv[k] * inv_s), -127.f), 127.f);
                xq[(long long)i * 1408 + c] = (signed char)(int)qv;
            }
        }
        return;
    }
    if (id < 5120) {
        // W_out transpose: 8192x64 f32 -> 128x8192 bf16 (zero-pad cols)
        const int r  = id - 4096;                 // 256 x 4
        const int k0 = (r & 255) * 32, n0 = (r >> 8) * 32;
        const int tx = tid & 31, ty = tid >> 5;
#pragma unroll
        for (int i = 0; i < 4; ++i) {
            const int k = k0 + ty + i * 8;
            const int n = n0 + tx;
            ts[ty + i * 8][tx] = (n < 64) ? W_out[(long long)k * 64 + n] : 0.f;
        }
        __syncthreads();
#pragma unroll
        for (int i = 0; i < 4; ++i) {
            const int n  = n0 + ty + i * 8;
            const int kk = k0 + tx;
            WoutT[(long long)n * 8192 + kk] = __float2bfloat16(ts[tx][ty + i * 8]);
        }
        return;
    }
    // ---- wa: wave per (h, c) ----
    {
        const int b = id - 5120;                     // 8 heads x 352
        const int h = b / 352, r = b % 352;
        const int wave = tid >> 6, lane = tid & 63;
        const int c = r * 4 + wave;                  // 0..1407
        float s1 = 0.f, s2 = 0.f;
        if (c < 1386) {
            const float* wr = W_att + ((long long)h * 1386 + c) * 1024;
            const float* a1 = a_att + (long long)h * 2048;
            const float* a2 = a1 + 1024;
#pragma unroll
            for (int t = 0; t < 16; ++t) {
                const int j = lane + t * 64;
                const float w = wr[j];
                s1 += w * a1[j];
                s2 += w * a2[j];
            }
        }
        for (int off = 32; off; off >>= 1) { s1 += __shfl_down(s1, off); s2 += __shfl_down(s2, off); }
        if (lane == 0 && c < 1386) {
            wa[(h * 2 + 0) * 1408 + c] = s1;
            wa[(h * 2 + 1) * 1408 + c] = s2;
        }
    }
}

// ---------------------------------------------------------------------------
// stage2: [0,528) SIM-i8 upper-triangle GEMM
//         [528,11792) transpose W_att (f32 (8,1386,1024) -> bf16 (8,1024,1408))
//         [11792,12816) f12 = x @ wa (wave per row, fp32)
// Memory-bound transpose + f12x overlap the compute-bound SIM.
// ---------------------------------------------------------------------------
__global__ __launch_bounds__(256, 2)
void stage2(const signed char* __restrict__ xq,
            const float* __restrict__ scales,
            const float* __restrict__ norms,
            unsigned* __restrict__ mask,
            unsigned* __restrict__ summ,
            const float* __restrict__ W_att,
            __hip_bfloat16* __restrict__ Wt_bf,
            const float* __restrict__ x,
            const float* __restrict__ wa,
            float2* __restrict__ f12)
{
    __shared__ __align__(16) __hip_bfloat16 As[128 * 32];
    __shared__ __align__(16) __hip_bfloat16 Bs[128 * 32];
    const int id = blockIdx.x;

    if (id < 528) {
        int t = (int)((sqrtf(8.f * id + 1.f) - 1.f) * 0.5f);
        while (t * (t + 1) / 2 > id) --t;
        while ((t + 1) * (t + 2) / 2 <= id) ++t;
        const int by = t, bx = id - t * (t + 1) / 2;   // bx <= by
        sim_i8_body((signed char*)As, (signed char*)Bs, bx, by,
                    xq, scales, norms, mask, summ);
        return;
    }
    if (id < 11792) {
        // W_att transpose, LDS overlaid on As
        float (*ts)[33] = (float(*)[33])As;
        const int tid = threadIdx.x;
        const int b = id - 528;                  // 8 heads x 44 x 32
        const int h = b / 1408, r = b % 1408;
        const int kx = r % 44, ny = r / 44;
        const float* s = W_att + (long long)h * 1386 * 1024;
        __hip_bfloat16* d = Wt_bf + (long long)h * 1024 * 1408;
        const int k0 = kx * 32, n0 = ny * 32;
        const int tx = tid & 31, ty = tid >> 5;
#pragma unroll
        for (int i = 0; i < 4; ++i) {
            const int k = k0 + ty + i * 8;
            const int n = n0 + tx;
            ts[ty + i * 8][tx] = (k < 1386) ? s[(long long)k * 1024 + n] : 0.f;
        }
        __syncthreads();
#pragma unroll
        for (int i = 0; i < 4; ++i) {
            const int n  = n0 + ty + i * 8;
            const int kk = k0 + tx;
            if (kk < 1408)
                d[(long long)n * 1408 + kk] = __float2bfloat16(ts[tx][ty + i * 8]);
        }
        return;
    }
    // ---- f12x: wave per row ----
    {
        const int b    = id - 11792;
        const int wave = threadIdx.x >> 6, lane = threadIdx.x & 63;
        const int i    = b * 4 + wave;
        float s[16];
#pragma unroll
        for (int j = 0; j < 16; ++j) s[j] = 0.f;
        const float* xr = x + (long long)i * 1386;
        for (int c = lane; c < 1386; c += 64) {
            const float v = xr[c];
#pragma unroll
            for (int j = 0; j < 16; ++j) s[j] += v * wa[j * 1408 + c];
        }
#pragma unroll
        for (int j = 0; j < 16; ++j)
            for (int off = 32; off; off >>= 1) s[j] += __shfl_down(s[j], off);
        if (lane == 0) {
#pragma unroll
            for (int h = 0; h < 8; ++h)
                f12[(long long)h * 4096 + i] = make_float2(s[h * 2], s[h * 2 + 1]);
        }
    }
}

// Wh GEMM for all 8 heads; epilogue routes per-row (hout direct vs Wh)
__global__ __launch_bounds__(256, 2)
void whh(const __hip_bfloat16* __restrict__ x_bf,
         const __hip_bfloat16* __restrict__ Wt_bf,
         __hip_bfloat16* __restrict__ Wh,
         __hip_bfloat16* __restrict__ hout,
         unsigned* __restrict__ mask,
         unsigned* __restrict__ summ)
{
    __shared__ __align__(16) __hip_bfloat16 As[128 * 64];
    __shared__ __align__(16) __hip_bfloat16 Bs[128 * 64];
    const int id = blockIdx.x;
    const int z  = id >> 8;            // head
    const int r  = id & 255;
    const int bx = r & 31, by = r >> 5;
    gemm_body<MODE_WH>(As, Bs, bx, by,
                       x_bf, Wt_bf + (long long)z * 1024 * 1408,
                       1408, 1408, 1408,
                       Wh + (long long)z * 4096 * 1024, 1024, 1024,
                       mask, summ, hout + (long long)z * 1024);
}

// out partial GEMM: split-K (16 chunks of 512, BK=64 -> 8 iters; 512 blocks)
__global__ __launch_bounds__(256, 2)
void out_gemm(const __hip_bfloat16* __restrict__ hout,
              const __hip_bfloat16* __restrict__ WoutT,
              float* __restrict__ parts)
{
    __shared__ __align__(16) __hip_bfloat16 As[128 * 64];
    __shared__ __align__(16) __hip_bfloat16 Bs[128 * 64];
    const int z = blockIdx.z;
    gemm_body<MODE_F32>(As, Bs, blockIdx.x, 0,
                        hout + z * 512, WoutT + z * 512, 8192, 8192, 512,
                        parts + (long long)z * 4096 * 64, 64, 64,
                        nullptr, nullptr, nullptr);
}

// fallback attention for non-degree-1 rows (early-exit otherwise); wave/(row,head)
__global__ __launch_bounds__(256)
void attn_fix(const __hip_bfloat16* __restrict__ Wh,
              const float2* __restrict__ f12,
              const unsigned* __restrict__ mask,
              const unsigned* __restrict__ summary,
              __hip_bfloat16* __restrict__ hout)
{
    const int wv   = threadIdx.x >> 6;
    const int lane = threadIdx.x & 63;
    const int i    = blockIdx.x * 4 + wv;
    const int h    = blockIdx.y;
    if (row_fast(mask, summary, i)) return;   // whh already wrote hout row

    const float2* f = f12 + (long long)h * 4096;
    const float f1 = f[i].x;
    const unsigned* mrow = mask + (long long)i * 128;
    const __hip_bfloat16* WhH = Wh + (long long)h * 4096 * 1024;
    const uint4 sm = *(const uint4*)(summary + (long long)i * 4);
    unsigned sw[4] = { sm.x, sm.y, sm.z, sm.w };
    const int cbase = lane * 16;

    float m = -INFINITY, l = 0.f;
    float acc[16];
#pragma unroll
    for (int k = 0; k < 16; ++k) acc[k] = 0.f;

#pragma unroll
    for (int s = 0; s < 4; ++s) {
        unsigned sb = sw[s];
        while (sb) {
            const int w = s * 32 + __builtin_ctz(sb);
            sb &= sb - 1;
            unsigned bits = mrow[w];
            while (bits) {
                const int j = w * 32 + __builtin_ctz(bits);
                bits &= bits - 1;
                float e = f1 + f[j].y;
                e = e > 0.f ? e : 0.2f * e;           // leaky_relu 0.2
                float wgt;
                if (e > m) {
                    const float sc = __expf(m - e);   // 0 on first iter
                    l *= sc;
#pragma unroll
                    for (int k = 0; k < 16; ++k) acc[k] *= sc;
                    m = e; wgt = 1.f;
                } else {
                    wgt = __expf(e - m);
                }
                l += wgt;
                const ushort8* p = (const ushort8*)(WhH + (long long)j * 1024 + cbase);
                const ushort8 w0 = p[0], w1 = p[1];
#pragma unroll
                for (int k = 0; k < 8; ++k) acc[k]     += wgt * bfbits2f(w0[k]);
#pragma unroll
                for (int k = 0; k < 8; ++k) acc[k + 8] += wgt * bfbits2f(w1[k]);
            }
        }
    }
    const float inv = 1.f / l;
    ushort8 o0, o1;
#pragma unroll
    for (int k = 0; k < 8; ++k) {
        float v = acc[k] * inv;     v = v > 0.f ? v : (__expf(v) - 1.f); o0[k] = f2bfbits(v);
        float u = acc[k + 8] * inv; u = u > 0.f ? u : (__expf(u) - 1.f); o1[k] = f2bfbits(u);
    }
    ushort8* op = (ushort8*)(hout + (long long)i * 8192 + (long long)h * 1024 + cbase);
    op[0] = o0; op[1] = o1;
}

// reduce 16 split-K parts -> Cout; f1o/f2o; fast rows: out = tanh(Cout) inline.
__global__ __launch_bounds__(256)
void out_finish(const float* __restrict__ parts,
                const float* __restrict__ a_out,
                float* __restrict__ Cout,
                float* __restrict__ f1o,
                float* __restrict__ f2o,
                const unsigned* __restrict__ mask,
                const unsigned* __restrict__ summ,
                float* __restrict__ out)
{
    const int wv = threadIdx.x >> 6;
    const int c  = threadIdx.x & 63;
    const int i  = blockIdx.x * 4 + wv;
    float v = 0.f;
#pragma unroll
    for (int z = 0; z < 16; ++z) v += parts[(long long)z * 4096 * 64 + (long long)i * 64 + c];
    Cout[(long long)i * 64 + c] = v;
    float s1 = v * a_out[c];
    float s2 = v * a_out[64 + c];
    for (int off = 32; off; off >>= 1) { s1 += __shfl_down(s1, off); s2 += __shfl_down(s2, off); }
    if (c == 0) { f1o[i] = s1; f2o[i] = s2; }
    if (row_fast(mask, summ, i))
        out[(long long)i * 64 + c] = tanhf(v);   // att = 1 exactly
}

// exceptional-row second layer attention + tanh (early-exit otherwise); wave/row
__global__ __launch_bounds__(256)
void attn_out_fix(const float* __restrict__ Cout,
                  const float* __restrict__ f1o,
                  const float* __restrict__ f2o,
                  const unsigned* __restrict__ mask,
                  const unsigned* __restrict__ summary,
                  float* __restrict__ out)
{
    const int wv = threadIdx.x >> 6;
    const int c  = threadIdx.x & 63;
    const int i  = blockIdx.x * 4 + wv;
    if (row_fast(mask, summary, i)) return;   // out_finish already wrote it
    const float f1 = f1o[i];
    const unsigned* mrow = mask + (long long)i * 128;
    const uint4 sm = *(const uint4*)(summary + (long long)i * 4);
    unsigned sw[4] = { sm.x, sm.y, sm.z, sm.w };
    float m = -INFINITY, l = 0.f, acc = 0.f;
#pragma unroll
    for (int s = 0; s < 4; ++s) {
        unsigned sb = sw[s];
        while (sb) {
            const int w = s * 32 + __builtin_ctz(sb);
            sb &= sb - 1;
            unsigned bits = mrow[w];
            while (bits) {
                const int j = w * 32 + __builtin_ctz(bits);
                bits &= bits - 1;
                float e = f1 + f2o[j];
                e = e > 0.f ? e : 0.2f * e;
                float wgt;
                if (e > m) { const float sc = __expf(m - e); l *= sc; acc *= sc; m = e; wgt = 1.f; }
                else       { wgt = __expf(e - m); }
                l += wgt;
                acc += wgt * Cout[(long long)j * 64 + c];
            }
        }
    }
    out[(long long)i * 64 + c] = tanhf(acc / l);
}

extern "C" void kernel_launch(void* const* d_in, const int* in_sizes, int n_in,
                              void* d_out, int out_size, void* d_ws, size_t ws_size,
                              hipStream_t stream)
{
    (void)in_sizes; (void)n_in; (void)out_size;
    const float* x     = (const float*)d_in[0];
    const float* W_att = (const float*)d_in[1];
    const float* a_att = (const float*)d_in[2];
    const float* W_out = (const float*)d_in[3];
    const float* a_out = (const float*)d_in[4];
    float* out = (float*)d_out;

    char* ws = (char*)d_ws;
    size_t off = 0;
    auto alloc = [&](size_t bytes) -> void* {
        void* p = ws + off;
        off += (bytes + 255) & ~(size_t)255;
        return p;
    };

    __hip_bfloat16* x_bf  = (__hip_bfloat16*)alloc(4096LL * 1408 * 2);
    signed char*    xq    = (signed char*)alloc(4096LL * 1408);
    __hip_bfloat16* Wt_bf = (__hip_bfloat16*)alloc(8LL * 1024 * 1408 * 2);
    __hip_bfloat16* WoutT = (__hip_bfloat16*)alloc(128LL * 8192 * 2);
    float*          norms = (float*)alloc(4096 * 4);
    float*          scales= (float*)alloc(4096 * 4);
    unsigned*       mask  = (unsigned*)alloc(4096LL * 128 * 4);
    unsigned*       summ  = (unsigned*)alloc(4096LL * 4 * 4);
    float*          wa    = (float*)alloc(16LL * 1408 * 4);
    float2*         f12   = (float2*)alloc(8LL * 4096 * 8);
    float*          parts = (float*)alloc(16LL * 4096 * 64 * 4);
    float*          Cout  = (float*)alloc(4096LL * 64 * 4);
    float*          f1o   = (float*)alloc(4096 * 4);
    float*          f2o   = (float*)alloc(4096 * 4);
    __hip_bfloat16* Wh    = (__hip_bfloat16*)alloc(8LL * 4096 * 1024 * 2);
    __hip_bfloat16* hout  = (__hip_bfloat16*)alloc(8LL * 4096 * 1024 * 2);
    if (off > ws_size) return;   // ws too small (~190 MB needed)

    // stage1 clears mask/summ (per-row) -- no memset dispatch needed
    stage1<<<7936, 256, 0, stream>>>(x, W_att, W_out, a_att,
                                     x_bf, xq, norms, scales, WoutT, wa,
                                     mask, summ);

    // SIM-i8 (compute) || W_att transpose (memory) || f12x; mask final after
    stage2<<<12816, 256, 0, stream>>>(xq, scales, norms, mask, summ,
                                      W_att, Wt_bf, x, wa, f12);

    whh<<<2048, 256, 0, stream>>>(x_bf, Wt_bf, Wh, hout, mask, summ);

    attn_fix<<<dim3(1024, 8), 256, 0, stream>>>(Wh, f12, mask, summ, hout);

    out_gemm<<<dim3(32, 1, 16), 256, 0, stream>>>(hout, WoutT, parts);

    out_finish<<<1024, 256, 0, stream>>>(parts, a_out, Cout, f1o, f2o,
                                         mask, summ, out);
    attn_out_fix<<<1024, 256, 0, stream>>>(Cout, f1o, f2o, mask, summ, out);
}